// Round 14
// baseline (50.411 us; speedup 1.0000x reference)
//
#include <hip/hip_runtime.h>
#include <hip/hip_bf16.h>

// Problem constants
constexpr int Bn = 4096;   // batch
constexpr int Vn = 64;     // nodes
constexpr int Hn = 512;    // hidden

typedef __attribute__((ext_vector_type(8))) short bf16x8;
typedef __attribute__((ext_vector_type(4))) float f32x4;
typedef __attribute__((ext_vector_type(8))) unsigned short u16x8;
typedef __attribute__((ext_vector_type(4))) _Float16 f16x4;
typedef __attribute__((ext_vector_type(2))) __fp16 fp16v2;

union h4cast { fp16v2 h2[2]; f16x4 f4; };

__device__ __forceinline__ unsigned short f2bf(float f) {
    union { float f; unsigned int u; } x; x.f = f;
    unsigned int u = x.u;
    u += 0x7fffu + ((u >> 16) & 1u);   // round-to-nearest-even
    return (unsigned short)(u >> 16);
}

// ---------------------------------------------------------------------------
// Prep (1152 blocks x 256): identical to R13.
//  blocks 0..1023: bfrag[v] = sigmoid(adj)*W1 in mfma frag layout (XCD-affine)
//  blocks 1024..1151: afrag = x fp32->bf16 in A-frag layout
// ---------------------------------------------------------------------------
__global__ void prep_all(const float* __restrict__ adjw,
                         const float* __restrict__ W1,
                         const float* __restrict__ x,
                         unsigned short* __restrict__ bfrag,
                         unsigned short* __restrict__ afrag) {
    if (blockIdx.x < 1024) {
        int nb   = (blockIdx.x & 7) * 128 + (blockIdx.x >> 3);
        int tid  = nb * 256 + threadIdx.x;
        int lane = tid & 63;
        int ks   = (tid >> 6) & 1;
        int nt   = (tid >> 7) & 31;
        int v    = tid >> 12;

        int n     = nt * 16 + (lane & 15);
        int kbase = ks * 32 + ((lane >> 4) << 3);

        u16x8 o;
#pragma unroll
        for (int e = 0; e < 8; ++e) {
            int k = kbase + e;
            float val = 0.f;
            if (k != v) {
                float aw = adjw[v * Vn + k];
                float s  = 1.f / (1.f + __expf(-aw));
                int  j   = k - (k > v);
                val = s * W1[((size_t)(v * (Vn - 1) + j)) * Hn + n];
            }
            o[e] = f2bf(val);
        }
        *reinterpret_cast<u16x8*>(bfrag + (size_t)tid * 8) = o;
    } else {
        int tid  = (blockIdx.x - 1024) * 256 + threadIdx.x;   // 0..32767
        int lane = tid & 63;
        int ks   = (tid >> 6) & 1;
        int mt   = tid >> 7;

        int b     = mt * 16 + (lane & 15);
        int kbase = ks * 32 + ((lane >> 4) << 3);

        u16x8 o;
#pragma unroll
        for (int e = 0; e < 8; ++e)
            o[e] = f2bf(x[(size_t)b * Vn + kbase + e]);
        *reinterpret_cast<u16x8*>(afrag + (size_t)tid * 8) = o;
    }
}

// ---------------------------------------------------------------------------
// Main: identical to R13 (one-shot staging, barrier-free 16 m-tiles).
// Launched TWICE this round (idempotent) purely to measure its duration:
// dur_us(R14) - dur_us(R13) = one main_k + one launch gap.
// ---------------------------------------------------------------------------
__global__ __launch_bounds__(512, 4)
void main_k(const unsigned short* __restrict__ afrag,
            const unsigned short* __restrict__ bfrag,
            const float* __restrict__ b1, const float* __restrict__ W2,
            const float* __restrict__ b2, float* __restrict__ out) {
    __shared__ __align__(16) unsigned char smem[32768 + 256 * 9 * 4];
    float* partials = reinterpret_cast<float*>(smem + 32768);

    int t    = threadIdx.x;
    int wid  = t >> 6;
    int lane = t & 63;
    // XCD-affine: all 16 ro-blocks of v live on XCD v>>3 (matches prep)
    int v    = (blockIdx.x & 7) * 8 + ((blockIdx.x >> 3) & 7);
    int ro   = blockIdx.x >> 6;            // 0..15, 256 rows each

    // ---- issue ALL staging loads up front (4x 16B/thread, coalesced) ----
    const u16x8* asrc = reinterpret_cast<const u16x8*>(afrag) + (size_t)ro * 2048;
    u16x8 s0 = asrc[t];
    u16x8 s1 = asrc[512 + t];
    u16x8 s2 = asrc[1024 + t];
    u16x8 s3 = asrc[1536 + t];

    // ---- persistent per-wave operands (coalesced from pre-digested data) ----
    const unsigned short* wpan = bfrag + (size_t)v * 32768;
    bf16x8 Wf[4][2];
#pragma unroll
    for (int j = 0; j < 4; ++j)
#pragma unroll
        for (int ks = 0; ks < 2; ++ks)
            Wf[j][ks] = *reinterpret_cast<const bf16x8*>(
                wpan + ((size_t)((wid * 4 + j) * 2 + ks)) * 512 + lane * 8);

    int hi4 = (lane >> 4) << 2;
    f32x4 b1bc[4];
    f16x4 w2A[4];
#pragma unroll
    for (int j = 0; j < 4; ++j) {
        int ntg = wid * 4 + j;
        b1bc[j] = *reinterpret_cast<const f32x4*>(b1 + v * Hn + ntg * 16 + hi4);
        f32x4 wv = *reinterpret_cast<const f32x4*>(W2 + v * Hn + ntg * 16 + hi4);
#pragma unroll
        for (int e = 0; e < 4; ++e) w2A[j][e] = (_Float16)wv[e];
    }

    // ---- write staged data, single barrier ----
    *reinterpret_cast<u16x8*>(smem + (size_t)t * 16)            = s0;
    *reinterpret_cast<u16x8*>(smem + (size_t)(512 + t) * 16)    = s1;
    *reinterpret_cast<u16x8*>(smem + (size_t)(1024 + t) * 16)   = s2;
    *reinterpret_cast<u16x8*>(smem + (size_t)(1536 + t) * 16)   = s3;
    __syncthreads();

    // ---- barrier-free compute: 16 m-tiles ----
#pragma unroll
    for (int mt = 0; mt < 16; ++mt) {
        bf16x8 a0 = *reinterpret_cast<const bf16x8*>(smem + ((mt * 2 + 0) * 64 + lane) * 16);
        bf16x8 a1 = *reinterpret_cast<const bf16x8*>(smem + ((mt * 2 + 1) * 64 + lane) * 16);
        f32x4 accA = {0.f, 0.f, 0.f, 0.f};
        f32x4 accB = {0.f, 0.f, 0.f, 0.f};
#pragma unroll
        for (int p = 0; p < 2; ++p) {
#pragma unroll
            for (int q = 0; q < 2; ++q) {
                int j = 2 * p + q;
                f32x4 c1 = __builtin_amdgcn_mfma_f32_16x16x32_bf16(Wf[j][0], a0, b1bc[j], 0, 0, 0);
                c1 = __builtin_amdgcn_mfma_f32_16x16x32_bf16(Wf[j][1], a1, c1, 0, 0, 0);
                h4cast hc;
                hc.h2[0] = __builtin_amdgcn_cvt_pkrtz(fmaxf(c1[0], 0.f), fmaxf(c1[1], 0.f));
                hc.h2[1] = __builtin_amdgcn_cvt_pkrtz(fmaxf(c1[2], 0.f), fmaxf(c1[3], 0.f));
                if (q == 0)
                    accA = __builtin_amdgcn_mfma_f32_16x16x16f16(w2A[j], hc.f4, accA, 0, 0, 0);
                else
                    accB = __builtin_amdgcn_mfma_f32_16x16x16f16(w2A[j], hc.f4, accB, 0, 0, 0);
            }
        }
        // D rows all equal (A broadcast); lanes 0..15 reg 0 = row 0
        if (lane < 16)
            partials[(mt * 16 + lane) * 9 + wid] = accA[0] + accB[0];
    }
    __syncthreads();

    // ---- final cross-wave reduce: thread t (<256) owns row ro*256+t ----
    if (t < 256) {
        float s = b2[v];
#pragma unroll
        for (int w = 0; w < 8; ++w) s += partials[t * 9 + w];
        out[(size_t)(ro * 256 + t) * Vn + v] = s;
    }
}

extern "C" void kernel_launch(void* const* d_in, const int* in_sizes, int n_in,
                              void* d_out, int out_size, void* d_ws, size_t ws_size,
                              hipStream_t stream) {
    const float* x    = (const float*)d_in[0];
    const float* adjw = (const float*)d_in[1];
    const float* W1   = (const float*)d_in[2];
    const float* b1   = (const float*)d_in[3];
    const float* W2   = (const float*)d_in[4];
    const float* b2   = (const float*)d_in[5];
    float* out = (float*)d_out;

    // workspace: bfrag = 64*64*512 u16 (4 MiB), afrag = 4096*64 u16 (512 KiB)
    unsigned short* bfrag = (unsigned short*)d_ws;
    unsigned short* afrag = bfrag + (size_t)Vn * Vn * Hn;

    prep_all<<<1152, 256, 0, stream>>>(adjw, W1, x, bfrag, afrag);
    // MEASUREMENT ROUND: main_k launched twice (idempotent).
    // dur_us(R14) - dur_us(R13) isolates one main_k duration.
    main_k<<<1024, 512, 0, stream>>>(afrag, bfrag, b1, W2, b2, out);
    main_k<<<1024, 512, 0, stream>>>(afrag, bfrag, b1, W2, b2, out);
}

// Round 15
// 33.169 us; speedup vs baseline: 1.5198x; 1.5198x over previous
//
#include <hip/hip_runtime.h>
#include <hip/hip_bf16.h>

// Problem constants
constexpr int Bn = 4096;   // batch
constexpr int Vn = 64;     // nodes
constexpr int Hn = 512;    // hidden

typedef __attribute__((ext_vector_type(8))) short bf16x8;
typedef __attribute__((ext_vector_type(4))) float f32x4;
typedef __attribute__((ext_vector_type(8))) unsigned short u16x8;
typedef __attribute__((ext_vector_type(4))) _Float16 f16x4;
typedef __attribute__((ext_vector_type(2))) __fp16 fp16v2;

union h4cast { fp16v2 h2[2]; f16x4 f4; };
union bfcast { u16x8 u; bf16x8 b; };

__device__ __forceinline__ unsigned short f2bf(float f) {
    union { float f; unsigned int u; } x; x.f = f;
    unsigned int u = x.u;
    u += 0x7fffu + ((u >> 16) & 1u);   // round-to-nearest-even
    return (unsigned short)(u >> 16);
}

// ---------------------------------------------------------------------------
// Prep (1024 blocks x 256): bfrag[v] = sigmoid(adj)*W1 in mfma frag layout,
// XCD-affine (panel v produced on XCD v>>3, same XCD that consumes it).
// R15: sigmoid via per-block LDS table — 64 exps/block (65K total) instead of
// the R13 per-thread-redundant 2M exps (~10 us of chip VALU, measured via the
// R14 double-launch split: prep+overhead was 10-12 us of the 30.4).
// ---------------------------------------------------------------------------
__global__ void prep_w1(const float* __restrict__ adjw,
                        const float* __restrict__ W1,
                        unsigned short* __restrict__ bfrag) {
    __shared__ float sig[Vn];
    int nb   = (blockIdx.x & 7) * 128 + (blockIdx.x >> 3);   // bijective, 1024
    int t    = threadIdx.x;
    int tid  = nb * 256 + t;
    int v    = tid >> 12;                                    // constant per block

    if (t < Vn) {
        float aw = adjw[v * Vn + t];
        sig[t] = (t == v) ? 0.f : 1.f / (1.f + __expf(-aw));
    }
    __syncthreads();

    int lane = tid & 63;
    int ks   = (tid >> 6) & 1;
    int nt   = (tid >> 7) & 31;

    int n     = nt * 16 + (lane & 15);
    int kbase = ks * 32 + ((lane >> 4) << 3);

    u16x8 o;
#pragma unroll
    for (int e = 0; e < 8; ++e) {
        int k = kbase + e;
        float val = 0.f;
        if (k != v)   // guard also avoids the OOB W1 row at k==v==63
            val = sig[k] * W1[((size_t)(v * (Vn - 1) + (k - (k > v)))) * Hn + n];
        o[e] = f2bf(val);
    }
    *reinterpret_cast<u16x8*>(bfrag + (size_t)tid * 8) = o;
}

// ---------------------------------------------------------------------------
// Main: 1024 blocks = (v, ro), ro in 0..15 (256 rows). 512 thr / 8 waves;
// wave w owns h-cols [w*64, w*64+64). ONE-SHOT staging directly from x
// (fp32->bf16 cvt fused into staging; afrag buffer eliminated): 4 frag slots
// per thread (t, t+512, t+1024, t+1536 -> m-tiles mt, mt+4, mt+8, mt+12),
// 8x f32x4 loads issued up front, ONE barrier, then 16 m-tiles barrier-free.
// Per mt: 8x mfma16x16x32_bf16 (b1 C-init), relu via packed cvt_pkrtz,
// 4x mfma16x16x16f16 W2-dot in two acc chains. Partials LDS stride-9.
// launch_bounds (512,4): VGPR cap 128 (R12 lesson: (512,6) forced spills).
// ---------------------------------------------------------------------------
__global__ __launch_bounds__(512, 4)
void main_k(const float* __restrict__ x,
            const unsigned short* __restrict__ bfrag,
            const float* __restrict__ b1, const float* __restrict__ W2,
            const float* __restrict__ b2, float* __restrict__ out) {
    __shared__ __align__(16) unsigned char smem[32768 + 256 * 9 * 4];
    float* partials = reinterpret_cast<float*>(smem + 32768);

    int t    = threadIdx.x;
    int wid  = t >> 6;
    int lane = t & 63;
    // XCD-affine: all 16 ro-blocks of v live on XCD v>>3 (matches prep)
    int v    = (blockIdx.x & 7) * 8 + ((blockIdx.x >> 3) & 7);
    int ro   = blockIdx.x >> 6;            // 0..15, 256 rows each

    // ---- issue ALL x staging loads up front (8x f32x4, 32B/slot) ----
    // slot g*512+t: mt = (t>>7)+4g, ks = (t>>6)&1, row = mt*16+(lane&15),
    // col = ks*32+(lane>>4)*8
    int s_mt  = t >> 7;
    int s_col = ((t >> 6) & 1) * 32 + ((lane >> 4) << 3);
    int s_row = ro * 256 + s_mt * 16 + (lane & 15);
    const float* xp0 = x + (size_t)s_row * Vn + s_col;
    f32x4 g0a = *reinterpret_cast<const f32x4*>(xp0);
    f32x4 g0b = *reinterpret_cast<const f32x4*>(xp0 + 4);
    const float* xp1 = xp0 + (size_t)64 * Vn;      // +4 m-tiles = +64 rows
    f32x4 g1a = *reinterpret_cast<const f32x4*>(xp1);
    f32x4 g1b = *reinterpret_cast<const f32x4*>(xp1 + 4);
    const float* xp2 = xp0 + (size_t)128 * Vn;
    f32x4 g2a = *reinterpret_cast<const f32x4*>(xp2);
    f32x4 g2b = *reinterpret_cast<const f32x4*>(xp2 + 4);
    const float* xp3 = xp0 + (size_t)192 * Vn;
    f32x4 g3a = *reinterpret_cast<const f32x4*>(xp3);
    f32x4 g3b = *reinterpret_cast<const f32x4*>(xp3 + 4);

    // ---- persistent per-wave operands (coalesced from pre-digested bfrag) ----
    const unsigned short* wpan = bfrag + (size_t)v * 32768;
    bf16x8 Wf[4][2];
#pragma unroll
    for (int j = 0; j < 4; ++j)
#pragma unroll
        for (int ks = 0; ks < 2; ++ks)
            Wf[j][ks] = *reinterpret_cast<const bf16x8*>(
                wpan + ((size_t)((wid * 4 + j) * 2 + ks)) * 512 + lane * 8);

    int hi4 = (lane >> 4) << 2;
    f32x4 b1bc[4];
    f16x4 w2A[4];
#pragma unroll
    for (int j = 0; j < 4; ++j) {
        int ntg = wid * 4 + j;
        b1bc[j] = *reinterpret_cast<const f32x4*>(b1 + v * Hn + ntg * 16 + hi4);
        f32x4 wv = *reinterpret_cast<const f32x4*>(W2 + v * Hn + ntg * 16 + hi4);
#pragma unroll
        for (int e = 0; e < 4; ++e) w2A[j][e] = (_Float16)wv[e];
    }

    // ---- cvt + write staged data, single barrier ----
    {
        bfcast c0, c1, c2, c3;
#pragma unroll
        for (int e = 0; e < 4; ++e) {
            c0.u[e] = f2bf(g0a[e]);  c0.u[e + 4] = f2bf(g0b[e]);
            c1.u[e] = f2bf(g1a[e]);  c1.u[e + 4] = f2bf(g1b[e]);
            c2.u[e] = f2bf(g2a[e]);  c2.u[e + 4] = f2bf(g2b[e]);
            c3.u[e] = f2bf(g3a[e]);  c3.u[e + 4] = f2bf(g3b[e]);
        }
        *reinterpret_cast<u16x8*>(smem + (size_t)t * 16)          = c0.u;
        *reinterpret_cast<u16x8*>(smem + (size_t)(512 + t) * 16)  = c1.u;
        *reinterpret_cast<u16x8*>(smem + (size_t)(1024 + t) * 16) = c2.u;
        *reinterpret_cast<u16x8*>(smem + (size_t)(1536 + t) * 16) = c3.u;
    }
    __syncthreads();

    // ---- barrier-free compute: 16 m-tiles ----
#pragma unroll
    for (int mt = 0; mt < 16; ++mt) {
        bf16x8 a0 = *reinterpret_cast<const bf16x8*>(smem + ((mt * 2 + 0) * 64 + lane) * 16);
        bf16x8 a1 = *reinterpret_cast<const bf16x8*>(smem + ((mt * 2 + 1) * 64 + lane) * 16);
        f32x4 accA = {0.f, 0.f, 0.f, 0.f};
        f32x4 accB = {0.f, 0.f, 0.f, 0.f};
#pragma unroll
        for (int p = 0; p < 2; ++p) {
#pragma unroll
            for (int q = 0; q < 2; ++q) {
                int j = 2 * p + q;
                f32x4 c1 = __builtin_amdgcn_mfma_f32_16x16x32_bf16(Wf[j][0], a0, b1bc[j], 0, 0, 0);
                c1 = __builtin_amdgcn_mfma_f32_16x16x32_bf16(Wf[j][1], a1, c1, 0, 0, 0);
                h4cast hc;
                hc.h2[0] = __builtin_amdgcn_cvt_pkrtz(fmaxf(c1[0], 0.f), fmaxf(c1[1], 0.f));
                hc.h2[1] = __builtin_amdgcn_cvt_pkrtz(fmaxf(c1[2], 0.f), fmaxf(c1[3], 0.f));
                if (q == 0)
                    accA = __builtin_amdgcn_mfma_f32_16x16x16f16(w2A[j], hc.f4, accA, 0, 0, 0);
                else
                    accB = __builtin_amdgcn_mfma_f32_16x16x16f16(w2A[j], hc.f4, accB, 0, 0, 0);
            }
        }
        // D rows all equal (A broadcast); lanes 0..15 reg 0 = row 0
        if (lane < 16)
            partials[(mt * 16 + lane) * 9 + wid] = accA[0] + accB[0];
    }
    __syncthreads();

    // ---- final cross-wave reduce: thread t (<256) owns row ro*256+t ----
    if (t < 256) {
        float s = b2[v];
#pragma unroll
        for (int w = 0; w < 8; ++w) s += partials[t * 9 + w];
        out[(size_t)(ro * 256 + t) * Vn + v] = s;
    }
}

extern "C" void kernel_launch(void* const* d_in, const int* in_sizes, int n_in,
                              void* d_out, int out_size, void* d_ws, size_t ws_size,
                              hipStream_t stream) {
    const float* x    = (const float*)d_in[0];
    const float* adjw = (const float*)d_in[1];
    const float* W1   = (const float*)d_in[2];
    const float* b1   = (const float*)d_in[3];
    const float* W2   = (const float*)d_in[4];
    const float* b2   = (const float*)d_in[5];
    float* out = (float*)d_out;

    // workspace: bfrag = 64*64*512 u16 (4 MiB)
    unsigned short* bfrag = (unsigned short*)d_ws;

    prep_w1<<<1024, 256, 0, stream>>>(adjw, W1, bfrag);
    main_k<<<1024, 512, 0, stream>>>(x, bfrag, b1, W2, b2, out);
}